// Round 7
// baseline (580.718 us; speedup 1.0000x reference)
//
#include <hip/hip_runtime.h>
#include <math.h>

#define NT 2048
#define HS 64
#define HNN 256
#define NSTEPS 1000
#define TSTEP 0.01f

typedef unsigned short u16;
typedef __attribute__((ext_vector_type(8))) short bf16x8;
typedef __attribute__((ext_vector_type(4))) float f32x4;

// ws layout (float offsets)
#define OFF_PINV 0         // 64*64
#define OFF_LAM  4096      // 64
#define OFF_B2P  4160      // 64
#define OFF_Q    4224      // 2*64
#define OFF_W2P  4352      // 64*256
#define OFF_LP   20736     // 1000*64 lam_pow[k][i]
#define OFF_LT   84736     // 64*1000 lamT[i][k]
#define OFF_HT   148736    // 256*2048 hT[j][c]; later reused for Yh/Yl bf16 frags
#define OFF_Y0   673024    // 64*2048

#define S_H 1028           // LDS stage stride (16 rows x 1028): 2-way banks, 64.2KB

// RNE f32 -> bf16 split: x ~= hi + lo (each bf16), err ~ 2^-18 |x|
__device__ inline void bsplit(float x, u16& hi, u16& lo) {
    unsigned u = __float_as_uint(x);
    unsigned r = (u + 0x7FFFu + ((u >> 16) & 1u)) >> 16;
    hi = (u16)r;
    float xh = __uint_as_float(r << 16);
    float d = x - xh;
    unsigned v = __float_as_uint(d);
    unsigned s = (v + 0x7FFFu + ((v >> 16) & 1u)) >> 16;
    lo = (u16)s;
}

// barrier that waits only LDS ops (lgkm), letting global stores stay in flight
__device__ inline void bar_lds() {
    asm volatile("s_waitcnt lgkmcnt(0)" ::: "memory");
    __builtin_amdgcn_s_barrier();
    asm volatile("" ::: "memory");
}

__device__ inline float tanh_fast(float x) {
    float xc = fminf(fmaxf(x, -15.f), 15.f);
    float a = __builtin_amdgcn_exp2f(xc * 2.885390082f);   // e^{2x}
    return (a - 1.f) * __builtin_amdgcn_rcpf(a + 1.f);
}

// ---------------- setup: unnormalized Gauss-Jordan (Pinv, lam, Q, b2p) ----------------
__global__ __launch_bounds__(256) void k_setup(const float* __restrict__ P,
                                               const float* __restrict__ D,
                                               const float* __restrict__ lm_w,
                                               const float* __restrict__ l2_b,
                                               float* __restrict__ ws) {
    __shared__ float Aug[64][130];
    int tid = threadIdx.x;
    int lane = tid & 63;

    for (int idx = tid; idx < 64 * 128; idx += 256) {
        int r = idx >> 7, c = idx & 127;
        Aug[r][c] = (c < 64) ? P[r * 64 + c] : ((c - 64) == r ? 1.f : 0.f);
    }
    __syncthreads();

    for (int j = 0; j < 64; ++j) {
        float v = (lane >= j) ? fabsf(Aug[lane][j]) : -1.f;
        int pi = lane;
        #pragma unroll
        for (int off = 32; off; off >>= 1) {
            float ov = __shfl_xor(v, off);
            int opi = __shfl_xor(pi, off);
            if (ov > v || (ov == v && opi < pi)) { v = ov; pi = opi; }
        }
        if (pi != j && tid < 128) {
            float a = Aug[j][tid], b = Aug[pi][tid];
            Aug[j][tid] = b; Aug[pi][tid] = a;
        }
        __syncthreads();
        int r = tid >> 2, c0 = (tid & 3) * 32;
        float f = Aug[r][j] / Aug[j][j];
        __syncthreads();
        if (r != j) {
            #pragma unroll
            for (int c = 0; c < 32; ++c) Aug[r][c0 + c] -= f * Aug[j][c0 + c];
        }
        __syncthreads();
    }

    for (int idx = tid; idx < 4096; idx += 256) {
        int r = idx >> 6, c = idx & 63;
        ws[OFF_PINV + idx] = Aug[r][64 + c] / Aug[r][r];
    }
    if (tid < 64) ws[OFF_LAM + tid] = 1.0f - TSTEP * expf(D[tid]);
    if (tid < 64) {
        float s = 0.f;
        for (int r = 0; r < 64; ++r) s += Aug[tid][64 + r] * l2_b[r];
        ws[OFF_B2P + tid] = s / Aug[tid][tid];
    }
    if (tid < 128) {
        int a = tid >> 6, i = tid & 63;
        float s = 0.f;
        for (int r = 0; r < 64; ++r) s += lm_w[a * 64 + r] * P[r * 64 + i];
        ws[OFF_Q + tid] = s;
    }
}

// ---------------- fused: ht (2048 blk) + w2p (64 blk) + lampow (250 blk) ----------------
__global__ __launch_bounds__(256) void k_fused(const float* __restrict__ target,
                                               const float* __restrict__ l1_w,
                                               const float* __restrict__ l1_b,
                                               const float* __restrict__ l2_w,
                                               float* __restrict__ ws) {
    int b = blockIdx.x;
    int tid = threadIdx.x;
    if (b < 2048) {
        int idx = b * 256 + tid;
        int j = idx >> 11, c = idx & 2047;
        const float2 t = ((const float2*)target)[c];
        float h = fmaf(l1_w[2 * j], t.x, fmaf(l1_w[2 * j + 1], t.y, l1_b[j]));
        ws[OFF_HT + j * NT + c] = fmaxf(h, 0.f);
    } else if (b < 2112) {
        int idx = (b - 2048) * 256 + tid;
        int i = idx >> 8, j = idx & 255;
        const float* Pinv = ws + OFF_PINV + i * 64;
        float a0 = 0, a1 = 0, a2 = 0, a3 = 0;
        #pragma unroll
        for (int r = 0; r < 64; r += 4) {
            a0 = fmaf(Pinv[r],     l2_w[r * 256 + j],       a0);
            a1 = fmaf(Pinv[r + 1], l2_w[(r + 1) * 256 + j], a1);
            a2 = fmaf(Pinv[r + 2], l2_w[(r + 2) * 256 + j], a2);
            a3 = fmaf(Pinv[r + 3], l2_w[(r + 3) * 256 + j], a3);
        }
        ws[OFF_W2P + idx] = (a0 + a1) + (a2 + a3);
    } else {
        int idx = (b - 2112) * 256 + tid;   // exactly 64000
        int k = idx >> 6, i = idx & 63;
        float l = ws[OFF_LAM + i];
        float p = exp2f((float)k * log2f(l));
        ws[OFF_LP + idx] = p;
        ws[OFF_LT + i * NSTEPS + k] = p;
    }
}

// ---------------- y0[i][c] = sum_j W2p[i][j] hT[j][c] + b2p[i] ----------------
__global__ __launch_bounds__(256) void k_y0(float* __restrict__ ws) {
    int idx = blockIdx.x * 256 + threadIdx.x;
    int i = idx >> 11, c = idx & 2047;
    const float* W2pi = ws + OFF_W2P + i * 256;
    const float* hT = ws + OFF_HT;
    float a0 = ws[OFF_B2P + i], a1 = 0, a2 = 0, a3 = 0;
    #pragma unroll 8
    for (int j = 0; j < 256; j += 4) {
        a0 = fmaf(W2pi[j],     hT[j * NT + c],       a0);
        a1 = fmaf(W2pi[j + 1], hT[(j + 1) * NT + c], a1);
        a2 = fmaf(W2pi[j + 2], hT[(j + 2) * NT + c], a2);
        a3 = fmaf(W2pi[j + 3], hT[(j + 3) * NT + c], a3);
    }
    ws[OFF_Y0 + i * NT + c] = (a0 + a1) + (a2 + a3);
}

// ---------------- y0 -> bf16 hi/lo fragments over dead hT region ----------------
// Layout: [ct(128)][kt(2)][lane(64)][j(8)]; elem = y0[kt*32+(lane>>4)*8+j][ct*16+(lane&15)]
__global__ __launch_bounds__(256) void k_yfrag(float* __restrict__ ws) {
    int idx = blockIdx.x * 256 + threadIdx.x;   // 16384
    int lane = idx & 63;
    int kt = (idx >> 6) & 1;
    int ct = idx >> 7;
    int c = ct * 16 + (lane & 15);
    int i0 = kt * 32 + (lane >> 4) * 8;
    const float* y0 = ws + OFF_Y0;
    u16* YH = (u16*)(ws + OFF_HT);
    u16* YL = YH + 131072;
    bf16x8 vh, vl;
    #pragma unroll
    for (int j = 0; j < 8; ++j) {
        u16 h, lo;
        bsplit(y0[(i0 + j) * NT + c], h, lo);
        vh[j] = (short)h;
        vl[j] = (short)lo;
    }
    int off = ((ct * 2 + kt) * 64 + lane);
    *(bf16x8*)(YH + off * 8) = vh;
    *(bf16x8*)(YL + off * 8) = vl;
}

// ---------------- main: hidden[k] = (P diag(lam^k)) @ y0, split-bf16 MFMA ----------------
// IDENTICAL to round 5/6.
__global__ __launch_bounds__(512, 2) void k_hidden(const float* __restrict__ P,
                                                   const float* __restrict__ ws,
                                                   float* __restrict__ hidden) {
    int k = blockIdx.x;
    int tid = threadIdx.x;
    int wid = tid >> 6, lane = tid & 63;
    int l15 = lane & 15, lg = lane >> 4;

    extern __shared__ float stage[];   // 16 * S_H floats = 65792 B

    const u16* YH = (const u16*)(ws + OFF_HT);
    const u16* YL = YH + 131072;
    const float* lp = ws + OFF_LP + k * 64;

    bf16x8 ah[4][2], al[4][2];
    #pragma unroll
    for (int rt = 0; rt < 4; ++rt) {
        int r = rt * 16 + l15;
        #pragma unroll
        for (int kt = 0; kt < 2; ++kt) {
            int i0 = kt * 32 + lg * 8;
            #pragma unroll
            for (int j = 0; j < 8; ++j) {
                float v = P[r * 64 + i0 + j] * lp[i0 + j];
                u16 h, lo;
                bsplit(v, h, lo);
                ah[rt][kt][j] = (short)h;
                al[rt][kt][j] = (short)lo;
            }
        }
    }

    float* outk = hidden + (size_t)k * 64 * NT;

    #pragma unroll 1
    for (int half = 0; half < 2; ++half) {
        bf16x8 bh[8][2], bl[8][2];
        #pragma unroll
        for (int q = 0; q < 8; ++q)
            #pragma unroll
            for (int kt = 0; kt < 2; ++kt) {
                int ct_g = half * 64 + wid * 8 + q;
                int off = ((ct_g * 2 + kt) * 64 + lane) * 8;
                bh[q][kt] = *(const bf16x8*)(YH + off);
                bl[q][kt] = *(const bf16x8*)(YL + off);
            }
        #pragma unroll
        for (int rt = 0; rt < 4; ++rt) {
            #pragma unroll
            for (int q = 0; q < 8; ++q) {
                f32x4 acc = {0.f, 0.f, 0.f, 0.f};
                #pragma unroll
                for (int kt = 0; kt < 2; ++kt) {
                    acc = __builtin_amdgcn_mfma_f32_16x16x32_bf16(ah[rt][kt], bh[q][kt], acc, 0, 0, 0);
                    acc = __builtin_amdgcn_mfma_f32_16x16x32_bf16(al[rt][kt], bh[q][kt], acc, 0, 0, 0);
                    acc = __builtin_amdgcn_mfma_f32_16x16x32_bf16(ah[rt][kt], bl[q][kt], acc, 0, 0, 0);
                }
                int col = wid * 128 + q * 16 + l15;
                #pragma unroll
                for (int reg = 0; reg < 4; ++reg)
                    stage[(lg * 4 + reg) * S_H + col] = acc[reg];
            }
            bar_lds();
            #pragma unroll
            for (int it = 0; it < 8; ++it) {
                int f = it * 512 + tid;            // float4 index, 0..4095
                int r = f >> 8, c4 = f & 255;
                float4 v = *(const float4*)&stage[r * S_H + (c4 << 2)];
                *(float4*)(outk + (size_t)(rt * 16 + r) * NT + half * 1024 + (c4 << 2)) = v;
            }
            bar_lds();
        }
    }
}

// ---------------- acts: 4 targets per block, float4 lamT loads, fast tanh ----------------
__global__ __launch_bounds__(256) void k_acts(const float* __restrict__ ws,
                                              const float* __restrict__ lm_b,
                                              float* __restrict__ actions) {
    int cbase = blockIdx.x * 4;
    int tid = threadIdx.x;
    __shared__ float us[4][128];
    for (int idx = tid; idx < 512; idx += 256) {
        int cg = idx >> 7, t = idx & 127;
        int a = t >> 6, i = t & 63;
        us[cg][t] = ws[OFF_Q + a * 64 + i] * ws[OFF_Y0 + i * NT + cbase + cg];
    }
    __syncthreads();
    if (tid >= 250) return;
    int k0 = tid * 4;
    float b0 = lm_b[0], b1 = lm_b[1];
    const float* lamT = ws + OFF_LT;
    float4 s[4][2];
    #pragma unroll
    for (int cg = 0; cg < 4; ++cg) {
        s[cg][0] = make_float4(b0, b0, b0, b0);
        s[cg][1] = make_float4(b1, b1, b1, b1);
    }
    #pragma unroll 4
    for (int i = 0; i < 64; ++i) {
        float4 v = *(const float4*)&lamT[i * NSTEPS + k0];
        #pragma unroll
        for (int cg = 0; cg < 4; ++cg) {
            float u0 = us[cg][i], u1 = us[cg][64 + i];
            s[cg][0].x = fmaf(u0, v.x, s[cg][0].x);
            s[cg][0].y = fmaf(u0, v.y, s[cg][0].y);
            s[cg][0].z = fmaf(u0, v.z, s[cg][0].z);
            s[cg][0].w = fmaf(u0, v.w, s[cg][0].w);
            s[cg][1].x = fmaf(u1, v.x, s[cg][1].x);
            s[cg][1].y = fmaf(u1, v.y, s[cg][1].y);
            s[cg][1].z = fmaf(u1, v.z, s[cg][1].z);
            s[cg][1].w = fmaf(u1, v.w, s[cg][1].w);
        }
    }
    #pragma unroll
    for (int cg = 0; cg < 4; ++cg)
        #pragma unroll
        for (int a = 0; a < 2; ++a) {
            float4 r;
            r.x = tanh_fast(s[cg][a].x);
            r.y = tanh_fast(s[cg][a].y);
            r.z = tanh_fast(s[cg][a].z);
            r.w = tanh_fast(s[cg][a].w);
            *(float4*)(actions + (size_t)(cbase + cg) * 2000 + a * 1000 + k0) = r;
        }
}

extern "C" void kernel_launch(void* const* d_in, const int* in_sizes, int n_in,
                              void* d_out, int out_size, void* d_ws, size_t ws_size,
                              hipStream_t stream) {
    const float* target = (const float*)d_in[0];
    const float* D      = (const float*)d_in[1];
    const float* P      = (const float*)d_in[2];
    const float* l1_w   = (const float*)d_in[3];
    const float* l1_b   = (const float*)d_in[4];
    const float* l2_w   = (const float*)d_in[5];
    const float* l2_b   = (const float*)d_in[6];
    const float* lm_w   = (const float*)d_in[7];
    const float* lm_b   = (const float*)d_in[8];
    float* ws = (float*)d_ws;
    float* actions = (float*)d_out;                  // 2048*2*1000
    float* hidden  = (float*)d_out + 4096000;        // 1000*64*2048

    hipFuncSetAttribute((const void*)k_hidden,
                        hipFuncAttributeMaxDynamicSharedMemorySize, 16 * S_H * 4);

    // MULTIPLICITY PROBE: all small kernels x3 (each idempotent; yfrag after
    // all y0 since yfrag overwrites hT). S = (total - 287.1)/2.
    hipLaunchKernelGGL(k_setup,  dim3(1),    dim3(256), 0, stream, P, D, lm_w, l2_b, ws);
    hipLaunchKernelGGL(k_setup,  dim3(1),    dim3(256), 0, stream, P, D, lm_w, l2_b, ws);
    hipLaunchKernelGGL(k_setup,  dim3(1),    dim3(256), 0, stream, P, D, lm_w, l2_b, ws);
    hipLaunchKernelGGL(k_fused,  dim3(2362), dim3(256), 0, stream, target, l1_w, l1_b, l2_w, ws);
    hipLaunchKernelGGL(k_fused,  dim3(2362), dim3(256), 0, stream, target, l1_w, l1_b, l2_w, ws);
    hipLaunchKernelGGL(k_fused,  dim3(2362), dim3(256), 0, stream, target, l1_w, l1_b, l2_w, ws);
    hipLaunchKernelGGL(k_y0,     dim3(512),  dim3(256), 0, stream, ws);
    hipLaunchKernelGGL(k_y0,     dim3(512),  dim3(256), 0, stream, ws);
    hipLaunchKernelGGL(k_y0,     dim3(512),  dim3(256), 0, stream, ws);
    hipLaunchKernelGGL(k_yfrag,  dim3(64),   dim3(256), 0, stream, ws);
    hipLaunchKernelGGL(k_yfrag,  dim3(64),   dim3(256), 0, stream, ws);
    hipLaunchKernelGGL(k_yfrag,  dim3(64),   dim3(256), 0, stream, ws);
    hipLaunchKernelGGL(k_hidden, dim3(1000), dim3(512), 16 * S_H * 4, stream, P, ws, hidden);
    hipLaunchKernelGGL(k_acts,   dim3(512),  dim3(256), 0, stream, ws, lm_b, actions);
    hipLaunchKernelGGL(k_acts,   dim3(512),  dim3(256), 0, stream, ws, lm_b, actions);
    hipLaunchKernelGGL(k_acts,   dim3(512),  dim3(256), 0, stream, ws, lm_b, actions);
}

// Round 8
// 232.896 us; speedup vs baseline: 2.4935x; 2.4935x over previous
//
#include <hip/hip_runtime.h>
#include <math.h>

#define NT 2048
#define HS 64
#define HNN 256
#define NSTEPS 1000
#define TSTEP 0.01f

typedef unsigned short u16;
typedef __attribute__((ext_vector_type(8))) short bf16x8;
typedef __attribute__((ext_vector_type(4))) float f32x4;

// ws layout (float offsets)
#define OFF_PINV 0         // 64*64
#define OFF_Q    4224      // 2*64
#define OFF_LP   20736     // 1000*64 lam_pow[k][i]
#define OFF_LT   84736     // 64*1000 lamT[i][k]
#define OFF_HT   148736    // bf16 frag region: YH (65536 f) + YL
#define OFF_Y0   673024    // 64*2048

#define S_H 1028           // k_hidden LDS stage stride

// RNE f32 -> bf16 split: x ~= hi + lo (each bf16), err ~ 2^-18 |x|
__device__ inline void bsplit(float x, u16& hi, u16& lo) {
    unsigned u = __float_as_uint(x);
    unsigned r = (u + 0x7FFFu + ((u >> 16) & 1u)) >> 16;
    hi = (u16)r;
    float xh = __uint_as_float(r << 16);
    float d = x - xh;
    unsigned v = __float_as_uint(d);
    unsigned s = (v + 0x7FFFu + ((v >> 16) & 1u)) >> 16;
    lo = (u16)s;
}

// barrier that waits only LDS ops (lgkm), letting global stores stay in flight
__device__ inline void bar_lds() {
    asm volatile("s_waitcnt lgkmcnt(0)" ::: "memory");
    __builtin_amdgcn_s_barrier();
    asm volatile("" ::: "memory");
}

__device__ inline float tanh_fast(float x) {
    float xc = fminf(fmaxf(x, -15.f), 15.f);
    float a = __builtin_amdgcn_exp2f(xc * 2.885390082f);   // e^{2x}
    return (a - 1.f) * __builtin_amdgcn_rcpf(a + 1.f);
}

// ---------------- k_pre: block0 = pipelined GJ inverse of P; 1..32 lampow; 33 Q ----
// Elimination: 1 barrier per iteration. Wave0 updates col t+1, selects pivot t+1,
// computes fvec_{t+1} (double-buffered); waves 1-7 update the other ~63 active cols
// of iteration t ({t+2..63} P-part + {64+piv[s]} activated I-part cols).
__global__ __launch_bounds__(512) void k_pre(const float* __restrict__ P,
                                             const float* __restrict__ D,
                                             const float* __restrict__ lm_w,
                                             float* __restrict__ ws) {
    int b = blockIdx.x;
    int tid = threadIdx.x;
    if (b == 0) {
        __shared__ float Aug[64 * 130];   // [P|I], stride 130 (2-way banks = free)
        __shared__ float fvec[2][64];
        __shared__ int s_piv[64];
        __shared__ int used[64];

        for (int idx = tid; idx < 64 * 128; idx += 512) {
            int r = idx >> 7, c = idx & 127;
            Aug[r * 130 + c] = (c < 64) ? P[r * 64 + c] : ((c - 64) == r ? 1.f : 0.f);
        }
        __syncthreads();

        // prologue: pivot + fvec for column 0
        if (tid < 64) {
            float nv = Aug[tid * 130];
            float v = fabsf(nv); int pi = tid;
            #pragma unroll
            for (int off = 32; off; off >>= 1) {
                float ov = __shfl_xor(v, off);
                int opi = __shfl_xor(pi, off);
                if (ov > v || (ov == v && opi < pi)) { v = ov; pi = opi; }
            }
            float pv = __shfl(nv, pi);
            fvec[0][tid] = (tid == pi) ? 0.f : nv / pv;
            used[tid] = (tid == pi) ? 1 : 0;
            if (tid == 0) s_piv[0] = pi;
        }
        __syncthreads();

        for (int t = 0; t < 64; ++t) {
            int p = s_piv[t];
            int par = t & 1;
            if (tid < 64) {
                // wave 0: update this iteration's "next" column, then pick next pivot
                int col0 = (t < 63) ? (t + 1) : (64 + s_piv[0]);
                float f = fvec[par][tid];
                float src = Aug[p * 130 + col0];
                float nv = Aug[tid * 130 + col0] - f * src;
                Aug[tid * 130 + col0] = nv;
                if (t < 63) {
                    float v = used[tid] ? -1.f : fabsf(nv);
                    int pi = tid;
                    #pragma unroll
                    for (int off = 32; off; off >>= 1) {
                        float ov = __shfl_xor(v, off);
                        int opi = __shfl_xor(pi, off);
                        if (ov > v || (ov == v && opi < pi)) { v = ov; pi = opi; }
                    }
                    float pv = __shfl(nv, pi);
                    fvec[par ^ 1][tid] = (tid == pi) ? 0.f : nv / pv;
                    if (tid == pi) used[tid] = 1;
                    if (tid == 0) s_piv[t + 1] = pi;
                }
            } else {
                // waves 1-7: iteration-t update on active cols s=1..63
                int w = (tid >> 6) - 1;          // 0..6
                int lane = tid & 63;
                float f = fvec[par][lane];
                const float* rowp = Aug + p * 130;
                float* rowr = Aug + lane * 130;
                int pcnt = 63 - t;               // count of remaining P-part cols (s<pcnt)
                for (int s = 1 + w; s < 64; s += 7) {
                    int col = (s < pcnt) ? (t + 1 + s) : (64 + s_piv[s - pcnt]);
                    rowr[col] -= f * rowp[col];
                }
            }
            __syncthreads();
        }

        // extraction: Pinv[j][m] = Aug[piv[j]][64+m] / Aug[piv[j]][j]
        for (int idx = tid; idx < 4096; idx += 512) {
            int j = idx >> 6, m = idx & 63;
            int pr = s_piv[j];
            ws[OFF_PINV + j * 64 + m] = Aug[pr * 130 + 64 + m] / Aug[pr * 130 + j];
        }
    } else if (b <= 32) {
        // lam powers: LP[k][i] and LT[i][k]; lam recomputed from D directly
        int base = ((b - 1) * 512 + tid) * 4;
        #pragma unroll
        for (int m = 0; m < 4; ++m) {
            int id = base + m;
            if (id < NSTEPS * 64) {
                int k = id >> 6, i = id & 63;
                float l = 1.0f - TSTEP * expf(D[i]);
                float pw = exp2f((float)k * log2f(l));
                ws[OFF_LP + id] = pw;
                ws[OFF_LT + i * NSTEPS + k] = pw;
            }
        }
    } else {
        // Q[a][i] = sum_r lm_w[a][r] * P[r][i]
        if (tid < 128) {
            int a = tid >> 6, i = tid & 63;
            float s = 0.f;
            for (int r = 0; r < 64; ++r) s = fmaf(lm_w[a * 64 + r], P[r * 64 + i], s);
            ws[OFF_Q + tid] = s;
        }
    }
}

// ---------------- k_y0f: per 16-col block: hT -> x0 -> y0 (=Pinv@x0) -> y0 + frags --
__global__ __launch_bounds__(256) void k_y0f(const float* __restrict__ target,
                                             const float* __restrict__ l1_w,
                                             const float* __restrict__ l1_b,
                                             const float* __restrict__ l2_w,
                                             const float* __restrict__ l2_b,
                                             float* __restrict__ ws) {
    int ct = blockIdx.x;                 // 0..127
    int cbase = ct * 16;
    int tid = threadIdx.x;
    __shared__ float tgt[16][2];
    __shared__ float shT[256 * 17];
    __shared__ float x0s[64 * 17];
    __shared__ float y0s[64 * 17];

    if (tid < 16) {
        float2 tv = ((const float2*)target)[cbase + tid];
        tgt[tid][0] = tv.x; tgt[tid][1] = tv.y;
    }
    __syncthreads();
    {   // hT row j = tid, 16 local columns
        float w0 = l1_w[2 * tid], w1 = l1_w[2 * tid + 1], bb = l1_b[tid];
        #pragma unroll
        for (int cc = 0; cc < 16; ++cc)
            shT[tid * 17 + cc] = fmaxf(fmaf(w0, tgt[cc][0], fmaf(w1, tgt[cc][1], bb)), 0.f);
    }
    __syncthreads();
    int i = tid >> 2, cs = (tid & 3) * 4;
    {   // x0[i][c] = l2_w[i,:] @ hT[:,c] + l2_b[i]
        const float* l2wi = l2_w + i * 256;
        float b = l2_b[i];
        float a0 = b, a1 = b, a2 = b, a3 = b;
        #pragma unroll 4
        for (int j = 0; j < 256; ++j) {
            float w = l2wi[j];
            const float* s = shT + j * 17 + cs;
            a0 = fmaf(w, s[0], a0); a1 = fmaf(w, s[1], a1);
            a2 = fmaf(w, s[2], a2); a3 = fmaf(w, s[3], a3);
        }
        x0s[i * 17 + cs + 0] = a0; x0s[i * 17 + cs + 1] = a1;
        x0s[i * 17 + cs + 2] = a2; x0s[i * 17 + cs + 3] = a3;
    }
    __syncthreads();
    {   // y0[i][c] = Pinv[i,:] @ x0[:,c]
        const float* Pinvi = ws + OFF_PINV + i * 64;
        float a0 = 0, a1 = 0, a2 = 0, a3 = 0;
        #pragma unroll 4
        for (int m = 0; m < 64; ++m) {
            float pv = Pinvi[m];
            const float* s = x0s + m * 17 + cs;
            a0 = fmaf(pv, s[0], a0); a1 = fmaf(pv, s[1], a1);
            a2 = fmaf(pv, s[2], a2); a3 = fmaf(pv, s[3], a3);
        }
        y0s[i * 17 + cs + 0] = a0; y0s[i * 17 + cs + 1] = a1;
        y0s[i * 17 + cs + 2] = a2; y0s[i * 17 + cs + 3] = a3;
    }
    __syncthreads();
    // y0 global
    float* y0 = ws + OFF_Y0;
    for (int idx = tid; idx < 1024; idx += 256) {
        int r = idx >> 4, cc = idx & 15;
        y0[r * NT + cbase + cc] = y0s[r * 17 + cc];
    }
    // frags (same layout k_hidden expects)
    if (tid < 128) {
        int kt = tid >> 6, lane = tid & 63;
        int c_l = lane & 15;
        int i0 = kt * 32 + (lane >> 4) * 8;
        u16* YH = (u16*)(ws + OFF_HT);
        u16* YL = YH + 131072;
        bf16x8 vh, vl;
        #pragma unroll
        for (int j = 0; j < 8; ++j) {
            u16 h, lo;
            bsplit(y0s[(i0 + j) * 17 + c_l], h, lo);
            vh[j] = (short)h; vl[j] = (short)lo;
        }
        int off = ((ct * 2 + kt) * 64 + lane);
        *(bf16x8*)(YH + off * 8) = vh;
        *(bf16x8*)(YL + off * 8) = vl;
    }
}

// ---------------- main: hidden[k] = (P diag(lam^k)) @ y0, split-bf16 MFMA ----------
// byte-identical structure to round 5/6 (measured ~107 us, ~78% of write floor)
__global__ __launch_bounds__(512, 2) void k_hidden(const float* __restrict__ P,
                                                   const float* __restrict__ ws,
                                                   float* __restrict__ hidden) {
    int k = blockIdx.x;
    int tid = threadIdx.x;
    int wid = tid >> 6, lane = tid & 63;
    int l15 = lane & 15, lg = lane >> 4;

    extern __shared__ float stage[];   // 16 * S_H floats = 65792 B

    const u16* YH = (const u16*)(ws + OFF_HT);
    const u16* YL = YH + 131072;
    const float* lp = ws + OFF_LP + k * 64;

    bf16x8 ah[4][2], al[4][2];
    #pragma unroll
    for (int rt = 0; rt < 4; ++rt) {
        int r = rt * 16 + l15;
        #pragma unroll
        for (int kt = 0; kt < 2; ++kt) {
            int i0 = kt * 32 + lg * 8;
            #pragma unroll
            for (int j = 0; j < 8; ++j) {
                float v = P[r * 64 + i0 + j] * lp[i0 + j];
                u16 h, lo;
                bsplit(v, h, lo);
                ah[rt][kt][j] = (short)h;
                al[rt][kt][j] = (short)lo;
            }
        }
    }

    float* outk = hidden + (size_t)k * 64 * NT;

    #pragma unroll 1
    for (int half = 0; half < 2; ++half) {
        bf16x8 bh[8][2], bl[8][2];
        #pragma unroll
        for (int q = 0; q < 8; ++q)
            #pragma unroll
            for (int kt = 0; kt < 2; ++kt) {
                int ct_g = half * 64 + wid * 8 + q;
                int off = ((ct_g * 2 + kt) * 64 + lane) * 8;
                bh[q][kt] = *(const bf16x8*)(YH + off);
                bl[q][kt] = *(const bf16x8*)(YL + off);
            }
        #pragma unroll
        for (int rt = 0; rt < 4; ++rt) {
            #pragma unroll
            for (int q = 0; q < 8; ++q) {
                f32x4 acc = {0.f, 0.f, 0.f, 0.f};
                #pragma unroll
                for (int kt = 0; kt < 2; ++kt) {
                    acc = __builtin_amdgcn_mfma_f32_16x16x32_bf16(ah[rt][kt], bh[q][kt], acc, 0, 0, 0);
                    acc = __builtin_amdgcn_mfma_f32_16x16x32_bf16(al[rt][kt], bh[q][kt], acc, 0, 0, 0);
                    acc = __builtin_amdgcn_mfma_f32_16x16x32_bf16(ah[rt][kt], bl[q][kt], acc, 0, 0, 0);
                }
                int col = wid * 128 + q * 16 + l15;
                #pragma unroll
                for (int reg = 0; reg < 4; ++reg)
                    stage[(lg * 4 + reg) * S_H + col] = acc[reg];
            }
            bar_lds();
            #pragma unroll
            for (int it = 0; it < 8; ++it) {
                int f = it * 512 + tid;            // float4 index, 0..4095
                int r = f >> 8, c4 = f & 255;
                float4 v = *(const float4*)&stage[r * S_H + (c4 << 2)];
                *(float4*)(outk + (size_t)(rt * 16 + r) * NT + half * 1024 + (c4 << 2)) = v;
            }
            bar_lds();
        }
    }
}

// ---------------- acts: 4 targets per block, float4 lamT loads, fast tanh ----------
__global__ __launch_bounds__(256) void k_acts(const float* __restrict__ ws,
                                              const float* __restrict__ lm_b,
                                              float* __restrict__ actions) {
    int cbase = blockIdx.x * 4;
    int tid = threadIdx.x;
    __shared__ float us[4][128];
    for (int idx = tid; idx < 512; idx += 256) {
        int cg = idx >> 7, t = idx & 127;
        int a = t >> 6, i = t & 63;
        us[cg][t] = ws[OFF_Q + a * 64 + i] * ws[OFF_Y0 + i * NT + cbase + cg];
    }
    __syncthreads();
    if (tid >= 250) return;
    int k0 = tid * 4;
    float b0 = lm_b[0], b1 = lm_b[1];
    const float* lamT = ws + OFF_LT;
    float4 s[4][2];
    #pragma unroll
    for (int cg = 0; cg < 4; ++cg) {
        s[cg][0] = make_float4(b0, b0, b0, b0);
        s[cg][1] = make_float4(b1, b1, b1, b1);
    }
    #pragma unroll 4
    for (int i = 0; i < 64; ++i) {
        float4 v = *(const float4*)&lamT[i * NSTEPS + k0];
        #pragma unroll
        for (int cg = 0; cg < 4; ++cg) {
            float u0 = us[cg][i], u1 = us[cg][64 + i];
            s[cg][0].x = fmaf(u0, v.x, s[cg][0].x);
            s[cg][0].y = fmaf(u0, v.y, s[cg][0].y);
            s[cg][0].z = fmaf(u0, v.z, s[cg][0].z);
            s[cg][0].w = fmaf(u0, v.w, s[cg][0].w);
            s[cg][1].x = fmaf(u1, v.x, s[cg][1].x);
            s[cg][1].y = fmaf(u1, v.y, s[cg][1].y);
            s[cg][1].z = fmaf(u1, v.z, s[cg][1].z);
            s[cg][1].w = fmaf(u1, v.w, s[cg][1].w);
        }
    }
    #pragma unroll
    for (int cg = 0; cg < 4; ++cg)
        #pragma unroll
        for (int a = 0; a < 2; ++a) {
            float4 r;
            r.x = tanh_fast(s[cg][a].x);
            r.y = tanh_fast(s[cg][a].y);
            r.z = tanh_fast(s[cg][a].z);
            r.w = tanh_fast(s[cg][a].w);
            *(float4*)(actions + (size_t)(cbase + cg) * 2000 + a * 1000 + k0) = r;
        }
}

extern "C" void kernel_launch(void* const* d_in, const int* in_sizes, int n_in,
                              void* d_out, int out_size, void* d_ws, size_t ws_size,
                              hipStream_t stream) {
    const float* target = (const float*)d_in[0];
    const float* D      = (const float*)d_in[1];
    const float* P      = (const float*)d_in[2];
    const float* l1_w   = (const float*)d_in[3];
    const float* l1_b   = (const float*)d_in[4];
    const float* l2_w   = (const float*)d_in[5];
    const float* l2_b   = (const float*)d_in[6];
    const float* lm_w   = (const float*)d_in[7];
    const float* lm_b   = (const float*)d_in[8];
    float* ws = (float*)d_ws;
    float* actions = (float*)d_out;                  // 2048*2*1000
    float* hidden  = (float*)d_out + 4096000;        // 1000*64*2048

    hipFuncSetAttribute((const void*)k_hidden,
                        hipFuncAttributeMaxDynamicSharedMemorySize, 16 * S_H * 4);

    hipLaunchKernelGGL(k_pre,    dim3(34),   dim3(512), 0, stream, P, D, lm_w, ws);
    hipLaunchKernelGGL(k_y0f,    dim3(128),  dim3(256), 0, stream, target, l1_w, l1_b, l2_w, l2_b, ws);
    hipLaunchKernelGGL(k_hidden, dim3(1000), dim3(512), 16 * S_H * 4, stream, P, ws, hidden);
    hipLaunchKernelGGL(k_acts,   dim3(512),  dim3(256), 0, stream, ws, lm_b, actions);
}